// Round 1
// baseline (1663.788 us; speedup 1.0000x reference)
//
#include <hip/hip_runtime.h>

#define B_DIM 8
#define S_LEN 4096
#define D_DIM 512
#define H_DIM 512

#define DECAY_F 0.90483743f   // exp(-0.1)
#define ALPHA_F 0.01f
#define EPS_F   1e-6f

// ---------------- GEMM: h[m][n] = sum_k x[m][k] * W[n][k] + bias[n] ----------------
// M = B*S = 32768, N = H = 512, K = D = 512. Both A and B are K-contiguous row-major.
__global__ __launch_bounds__(256) void gemm_kernel(const float* __restrict__ x,
                                                   const float* __restrict__ W,
                                                   const float* __restrict__ bias,
                                                   float* __restrict__ out) {
    __shared__ float As[64][17];
    __shared__ float Bs[64][17];

    const int tid = threadIdx.x;
    const int tx = tid & 15;     // 0..15 -> n sub-tile
    const int ty = tid >> 4;     // 0..15 -> m sub-tile
    const int bm = blockIdx.y * 64;
    const int bn = blockIdx.x * 64;

    const int lrow = tid >> 2;          // 0..63
    const int lc4  = (tid & 3) * 4;     // 0,4,8,12

    float acc[4][4];
#pragma unroll
    for (int i = 0; i < 4; ++i)
#pragma unroll
        for (int j = 0; j < 4; ++j) acc[i][j] = 0.f;

    for (int kk = 0; kk < D_DIM; kk += 16) {
        const float4 av = *reinterpret_cast<const float4*>(
            &x[(size_t)(bm + lrow) * D_DIM + kk + lc4]);
        const float4 bv = *reinterpret_cast<const float4*>(
            &W[(size_t)(bn + lrow) * D_DIM + kk + lc4]);
        As[lrow][lc4 + 0] = av.x;
        As[lrow][lc4 + 1] = av.y;
        As[lrow][lc4 + 2] = av.z;
        As[lrow][lc4 + 3] = av.w;
        Bs[lrow][lc4 + 0] = bv.x;
        Bs[lrow][lc4 + 1] = bv.y;
        Bs[lrow][lc4 + 2] = bv.z;
        Bs[lrow][lc4 + 3] = bv.w;
        __syncthreads();

#pragma unroll
        for (int k = 0; k < 16; ++k) {
            float a0 = As[ty * 4 + 0][k];
            float a1 = As[ty * 4 + 1][k];
            float a2 = As[ty * 4 + 2][k];
            float a3 = As[ty * 4 + 3][k];
            float b0 = Bs[tx * 4 + 0][k];
            float b1 = Bs[tx * 4 + 1][k];
            float b2 = Bs[tx * 4 + 2][k];
            float b3 = Bs[tx * 4 + 3][k];
            acc[0][0] += a0 * b0; acc[0][1] += a0 * b1; acc[0][2] += a0 * b2; acc[0][3] += a0 * b3;
            acc[1][0] += a1 * b0; acc[1][1] += a1 * b1; acc[1][2] += a1 * b2; acc[1][3] += a1 * b3;
            acc[2][0] += a2 * b0; acc[2][1] += a2 * b1; acc[2][2] += a2 * b2; acc[2][3] += a2 * b3;
            acc[3][0] += a3 * b0; acc[3][1] += a3 * b1; acc[3][2] += a3 * b2; acc[3][3] += a3 * b3;
        }
        __syncthreads();
    }

#pragma unroll
    for (int i = 0; i < 4; ++i) {
        const size_t row = (size_t)(bm + ty * 4 + i);
#pragma unroll
        for (int j = 0; j < 4; ++j) {
            const int col = bn + tx * 4 + j;
            out[row * H_DIM + col] = acc[i][j] + bias[col];
        }
    }
}

// ---------------- Scan: sequential GIF neuron update over S, one thread per (b,h) chain ----------------
// Reads h (dense currents) from io[] and overwrites with spikes in-place.
__global__ __launch_bounds__(64) void scan_kernel(float* __restrict__ io,
                                                  float* __restrict__ vout,
                                                  float* __restrict__ thout) {
    const int chain = blockIdx.x * 64 + threadIdx.x;   // 0..4095
    const int b = chain >> 9;                          // /512
    const int h = chain & 511;

    const size_t base = (size_t)b * S_LEN * H_DIM + h;

    float v = 0.f;
    float theta = 1.f;

    constexpr int PF = 16;
    float buf[PF];
#pragma unroll
    for (int i = 0; i < PF; ++i) buf[i] = io[base + (size_t)i * H_DIM];

    for (int s = 0; s < S_LEN; s += PF) {
#pragma unroll
        for (int u = 0; u < PF; ++u) {
            const float it = buf[u];
            // prefetch PF steps ahead (statically indexed -> stays in registers)
            const int sp = s + PF + u;
            if (sp < S_LEN) buf[u] = io[base + (size_t)sp * H_DIM];

            v = v * DECAY_F + it;
            const float cl = 32.f * theta;                 // L * theta * 2
            v = fminf(fmaxf(v, -cl), cl);
            const float nv = v / (theta + EPS_F);
            float spike = floorf(nv);
            spike = fminf(fmaxf(spike, 0.f), 16.f);
            v = v - spike * theta;
            theta = theta + ALPHA_F * spike - ALPHA_F * (theta - 1.0f);

            io[base + (size_t)(s + u) * H_DIM] = spike;
        }
    }

    vout[chain]  = v;
    thout[chain] = theta;
}

extern "C" void kernel_launch(void* const* d_in, const int* in_sizes, int n_in,
                              void* d_out, int out_size, void* d_ws, size_t ws_size,
                              hipStream_t stream) {
    const float* x    = (const float*)d_in[0];
    const float* W    = (const float*)d_in[1];
    const float* bias = (const float*)d_in[2];

    float* out   = (float*)d_out;
    float* vout  = out + (size_t)B_DIM * S_LEN * H_DIM;
    float* thout = vout + B_DIM * H_DIM;

    // GEMM writes dense currents h into the spikes region of d_out.
    dim3 grid(H_DIM / 64, (B_DIM * S_LEN) / 64);
    gemm_kernel<<<grid, 256, 0, stream>>>(x, W, bias, out);

    // Scan reads h and overwrites with spikes in-place; writes v/theta tails.
    scan_kernel<<<64, 64, 0, stream>>>(out, vout, thout);
}

// Round 2
// 463.971 us; speedup vs baseline: 3.5860x; 3.5860x over previous
//
#include <hip/hip_runtime.h>

#define B_DIM 8
#define S_LEN 4096
#define D_DIM 512
#define H_DIM 512

#define DECAY_F 0.90483743f   // exp(-0.1)
#define ALPHA_F 0.01f
#define EPS_F   1e-6f

// ---------------- GEMM: h[m][n] = sum_k x[m][k] * W[n][k] + bias[n] ----------------
// M = B*S = 32768, N = H = 512, K = D = 512. 128x128 tile, KT=16, 8x8 per thread.
// k-accumulation order identical to R1 (sequential k, fma, bias at end) -> bit-identical h.
#define KT 16
__global__ __launch_bounds__(256) void gemm_kernel(const float* __restrict__ x,
                                                   const float* __restrict__ W,
                                                   const float* __restrict__ bias,
                                                   float* __restrict__ out) {
    // k-major transposed tiles: column k contiguous in m. +4 pad keeps 16B align, ~2-way banks.
    __shared__ float As[KT][132];
    __shared__ float Bs[KT][132];

    const int tid = threadIdx.x;
    const int tx = tid & 15;     // n sub-tile 0..15
    const int ty = tid >> 4;     // m sub-tile 0..15
    const int bm = blockIdx.y * 128;
    const int bn = blockIdx.x * 128;

    const int lrow = tid >> 2;          // 0..63
    const int lk4  = (tid & 3) * 4;     // 0,4,8,12

    const float* xa = &x[(size_t)(bm + lrow) * D_DIM + lk4];
    const float* xb = &x[(size_t)(bm + lrow + 64) * D_DIM + lk4];
    const float* wa = &W[(size_t)(bn + lrow) * D_DIM + lk4];
    const float* wb = &W[(size_t)(bn + lrow + 64) * D_DIM + lk4];

    float acc[8][8];
#pragma unroll
    for (int i = 0; i < 8; ++i)
#pragma unroll
        for (int j = 0; j < 8; ++j) acc[i][j] = 0.f;

    for (int kk = 0; kk < D_DIM; kk += KT) {
        const float4 a0 = *reinterpret_cast<const float4*>(xa + kk);
        const float4 a1 = *reinterpret_cast<const float4*>(xb + kk);
        const float4 b0 = *reinterpret_cast<const float4*>(wa + kk);
        const float4 b1 = *reinterpret_cast<const float4*>(wb + kk);

        __syncthreads();
        As[lk4 + 0][lrow]      = a0.x;
        As[lk4 + 1][lrow]      = a0.y;
        As[lk4 + 2][lrow]      = a0.z;
        As[lk4 + 3][lrow]      = a0.w;
        As[lk4 + 0][lrow + 64] = a1.x;
        As[lk4 + 1][lrow + 64] = a1.y;
        As[lk4 + 2][lrow + 64] = a1.z;
        As[lk4 + 3][lrow + 64] = a1.w;
        Bs[lk4 + 0][lrow]      = b0.x;
        Bs[lk4 + 1][lrow]      = b0.y;
        Bs[lk4 + 2][lrow]      = b0.z;
        Bs[lk4 + 3][lrow]      = b0.w;
        Bs[lk4 + 0][lrow + 64] = b1.x;
        Bs[lk4 + 1][lrow + 64] = b1.y;
        Bs[lk4 + 2][lrow + 64] = b1.z;
        Bs[lk4 + 3][lrow + 64] = b1.w;
        __syncthreads();

#pragma unroll
        for (int k = 0; k < KT; ++k) {
            const float4 av0 = *reinterpret_cast<const float4*>(&As[k][ty * 8]);
            const float4 av1 = *reinterpret_cast<const float4*>(&As[k][ty * 8 + 4]);
            const float4 bv0 = *reinterpret_cast<const float4*>(&Bs[k][tx * 8]);
            const float4 bv1 = *reinterpret_cast<const float4*>(&Bs[k][tx * 8 + 4]);
            const float am[8] = {av0.x, av0.y, av0.z, av0.w, av1.x, av1.y, av1.z, av1.w};
            const float bn_[8] = {bv0.x, bv0.y, bv0.z, bv0.w, bv1.x, bv1.y, bv1.z, bv1.w};
#pragma unroll
            for (int i = 0; i < 8; ++i)
#pragma unroll
                for (int j = 0; j < 8; ++j) acc[i][j] += am[i] * bn_[j];
        }
    }

    const float4 bias0 = *reinterpret_cast<const float4*>(&bias[bn + tx * 8]);
    const float4 bias1 = *reinterpret_cast<const float4*>(&bias[bn + tx * 8 + 4]);
    const float bb[8] = {bias0.x, bias0.y, bias0.z, bias0.w, bias1.x, bias1.y, bias1.z, bias1.w};

#pragma unroll
    for (int i = 0; i < 8; ++i) {
        const size_t row = (size_t)(bm + ty * 8 + i);
        float4 o0, o1;
        o0.x = acc[i][0] + bb[0]; o0.y = acc[i][1] + bb[1];
        o0.z = acc[i][2] + bb[2]; o0.w = acc[i][3] + bb[3];
        o1.x = acc[i][4] + bb[4]; o1.y = acc[i][5] + bb[5];
        o1.z = acc[i][6] + bb[6]; o1.w = acc[i][7] + bb[7];
        *reinterpret_cast<float4*>(&out[row * H_DIM + bn + tx * 8])     = o0;
        *reinterpret_cast<float4*>(&out[row * H_DIM + bn + tx * 8 + 4]) = o1;
    }
}

// ---------------- Scan: sequential GIF neuron update, one thread per (b,h) chain ----------------
// Chunked double-buffer: burst-load next 32 h's, compute 32 steps from registers.
__global__ __launch_bounds__(64) void scan_kernel(float* __restrict__ io,
                                                  float* __restrict__ vout,
                                                  float* __restrict__ thout) {
    const int chain = blockIdx.x * 64 + threadIdx.x;   // 0..4095
    const int b = chain >> 9;                          // /512
    const int h = chain & 511;

    const size_t base = (size_t)b * S_LEN * H_DIM + h;

    float v = 0.f;
    float theta = 1.f;

    constexpr int PF = 32;
    float cur[PF], nxt[PF];
#pragma unroll
    for (int i = 0; i < PF; ++i) cur[i] = io[base + (size_t)i * H_DIM];

    for (int s = 0; s < S_LEN; s += PF) {
        const int sn = s + PF;
        if (sn < S_LEN) {
#pragma unroll
            for (int i = 0; i < PF; ++i) nxt[i] = io[base + (size_t)(sn + i) * H_DIM];
        }

#pragma unroll
        for (int u = 0; u < PF; ++u) {
            const float it = cur[u];
            v = v * DECAY_F + it;
            const float cl = 32.f * theta;                 // L * theta * 2
            v = fminf(fmaxf(v, -cl), cl);
            const float nv = v / (theta + EPS_F);
            float spike = floorf(nv);
            spike = fminf(fmaxf(spike, 0.f), 16.f);
            v = v - spike * theta;
            theta = theta + ALPHA_F * spike - ALPHA_F * (theta - 1.0f);
            io[base + (size_t)(s + u) * H_DIM] = spike;
        }

#pragma unroll
        for (int i = 0; i < PF; ++i) cur[i] = nxt[i];
    }

    vout[chain]  = v;
    thout[chain] = theta;
}

extern "C" void kernel_launch(void* const* d_in, const int* in_sizes, int n_in,
                              void* d_out, int out_size, void* d_ws, size_t ws_size,
                              hipStream_t stream) {
    const float* x    = (const float*)d_in[0];
    const float* W    = (const float*)d_in[1];
    const float* bias = (const float*)d_in[2];

    float* out   = (float*)d_out;
    float* vout  = out + (size_t)B_DIM * S_LEN * H_DIM;
    float* thout = vout + B_DIM * H_DIM;

    // GEMM writes dense currents h into the spikes region of d_out.
    dim3 grid(H_DIM / 128, (B_DIM * S_LEN) / 128);
    gemm_kernel<<<grid, 256, 0, stream>>>(x, W, bias, out);

    // Scan reads h and overwrites with spikes in-place; writes v/theta tails.
    scan_kernel<<<64, 64, 0, stream>>>(out, vout, thout);
}

// Round 3
// 450.948 us; speedup vs baseline: 3.6895x; 1.0289x over previous
//
#include <hip/hip_runtime.h>

#define B_DIM 8
#define S_LEN 4096
#define D_DIM 512
#define H_DIM 512

#define DECAY_F 0.90483743f   // exp(-0.1)
#define ALPHA_F 0.01f
#define EPS_F   1e-6f

// ---------------- GEMM: h[m][n] = sum_k x[m][k] * W[n][k] + bias[n] ----------------
// M = B*S = 32768, N = H = 512, K = D = 512. 128x128 tile, KT=16, 8x8 per thread.
// Register-staged double buffer: next K-tile's global loads issue before the FMA loop.
// k-accumulation order identical to R2 -> bit-identical h.
#define KT 16
__global__ __launch_bounds__(256) void gemm_kernel(const float* __restrict__ x,
                                                   const float* __restrict__ W,
                                                   const float* __restrict__ bias,
                                                   float* __restrict__ out) {
    __shared__ float As[KT][132];
    __shared__ float Bs[KT][132];

    const int tid = threadIdx.x;
    const int tx = tid & 15;     // n sub-tile 0..15
    const int ty = tid >> 4;     // m sub-tile 0..15
    const int bm = blockIdx.y * 128;
    const int bn = blockIdx.x * 128;

    const int lrow = tid >> 2;          // 0..63
    const int lk4  = (tid & 3) * 4;     // 0,4,8,12

    const float* xa = &x[(size_t)(bm + lrow) * D_DIM + lk4];
    const float* xb = &x[(size_t)(bm + lrow + 64) * D_DIM + lk4];
    const float* wa = &W[(size_t)(bn + lrow) * D_DIM + lk4];
    const float* wb = &W[(size_t)(bn + lrow + 64) * D_DIM + lk4];

    float acc[8][8];
#pragma unroll
    for (int i = 0; i < 8; ++i)
#pragma unroll
        for (int j = 0; j < 8; ++j) acc[i][j] = 0.f;

    // prologue: stage tile kk=0 into registers
    float4 a0 = *reinterpret_cast<const float4*>(xa);
    float4 a1 = *reinterpret_cast<const float4*>(xb);
    float4 b0 = *reinterpret_cast<const float4*>(wa);
    float4 b1 = *reinterpret_cast<const float4*>(wb);

    for (int kk = 0; kk < D_DIM; kk += KT) {
        __syncthreads();
        As[lk4 + 0][lrow]      = a0.x;
        As[lk4 + 1][lrow]      = a0.y;
        As[lk4 + 2][lrow]      = a0.z;
        As[lk4 + 3][lrow]      = a0.w;
        As[lk4 + 0][lrow + 64] = a1.x;
        As[lk4 + 1][lrow + 64] = a1.y;
        As[lk4 + 2][lrow + 64] = a1.z;
        As[lk4 + 3][lrow + 64] = a1.w;
        Bs[lk4 + 0][lrow]      = b0.x;
        Bs[lk4 + 1][lrow]      = b0.y;
        Bs[lk4 + 2][lrow]      = b0.z;
        Bs[lk4 + 3][lrow]      = b0.w;
        Bs[lk4 + 0][lrow + 64] = b1.x;
        Bs[lk4 + 1][lrow + 64] = b1.y;
        Bs[lk4 + 2][lrow + 64] = b1.z;
        Bs[lk4 + 3][lrow + 64] = b1.w;
        __syncthreads();

        // issue next tile's loads; latency hides under the FMA loop below
        if (kk + KT < D_DIM) {
            a0 = *reinterpret_cast<const float4*>(xa + kk + KT);
            a1 = *reinterpret_cast<const float4*>(xb + kk + KT);
            b0 = *reinterpret_cast<const float4*>(wa + kk + KT);
            b1 = *reinterpret_cast<const float4*>(wb + kk + KT);
        }

#pragma unroll
        for (int k = 0; k < KT; ++k) {
            const float4 av0 = *reinterpret_cast<const float4*>(&As[k][ty * 8]);
            const float4 av1 = *reinterpret_cast<const float4*>(&As[k][ty * 8 + 4]);
            const float4 bv0 = *reinterpret_cast<const float4*>(&Bs[k][tx * 8]);
            const float4 bv1 = *reinterpret_cast<const float4*>(&Bs[k][tx * 8 + 4]);
            const float am[8] = {av0.x, av0.y, av0.z, av0.w, av1.x, av1.y, av1.z, av1.w};
            const float bn_[8] = {bv0.x, bv0.y, bv0.z, bv0.w, bv1.x, bv1.y, bv1.z, bv1.w};
#pragma unroll
            for (int i = 0; i < 8; ++i)
#pragma unroll
                for (int j = 0; j < 8; ++j) acc[i][j] += am[i] * bn_[j];
        }
    }

    const float4 bias0 = *reinterpret_cast<const float4*>(&bias[bn + tx * 8]);
    const float4 bias1 = *reinterpret_cast<const float4*>(&bias[bn + tx * 8 + 4]);
    const float bb[8] = {bias0.x, bias0.y, bias0.z, bias0.w, bias1.x, bias1.y, bias1.z, bias1.w};

#pragma unroll
    for (int i = 0; i < 8; ++i) {
        const size_t row = (size_t)(bm + ty * 8 + i);
        float4 o0, o1;
        o0.x = acc[i][0] + bb[0]; o0.y = acc[i][1] + bb[1];
        o0.z = acc[i][2] + bb[2]; o0.w = acc[i][3] + bb[3];
        o1.x = acc[i][4] + bb[4]; o1.y = acc[i][5] + bb[5];
        o1.z = acc[i][6] + bb[6]; o1.w = acc[i][7] + bb[7];
        *reinterpret_cast<float4*>(&out[row * H_DIM + bn + tx * 8])     = o0;
        *reinterpret_cast<float4*>(&out[row * H_DIM + bn + tx * 8 + 4]) = o1;
    }
}

// ---------------- Scan: sequential GIF neuron update, one thread per (b,h) chain ----------------
// Ping-pong register buffers; loads for chunk n+2 issue right after chunk n is consumed,
// fenced with sched_barrier so they stay ahead of the next compute phase.
#define STEP(IT, SIDX) do {                                      \
        const float it = (IT);                                   \
        v = v * DECAY_F + it;                                    \
        const float cl = 32.f * theta;                           \
        v = fminf(fmaxf(v, -cl), cl);                            \
        const float nv = v / (theta + EPS_F);                    \
        float spike = floorf(nv);                                \
        spike = fminf(fmaxf(spike, 0.f), 16.f);                  \
        v = v - spike * theta;                                   \
        theta = theta + ALPHA_F * spike - ALPHA_F * (theta - 1.0f); \
        pio[(size_t)(SIDX) * H_DIM] = spike;                     \
    } while (0)

__global__ __launch_bounds__(64, 1) void scan_kernel(float* __restrict__ io,
                                                     float* __restrict__ vout,
                                                     float* __restrict__ thout) {
    const int chain = blockIdx.x * 64 + threadIdx.x;   // 0..4095
    const int b = chain >> 9;                          // /512
    const int h = chain & 511;

    float* pio = io + (size_t)b * S_LEN * H_DIM + h;

    float v = 0.f;
    float theta = 1.f;

    constexpr int PF = 32;
    float bufA[PF], bufB[PF];

#pragma unroll
    for (int i = 0; i < PF; ++i) bufA[i] = pio[(size_t)i * H_DIM];
#pragma unroll
    for (int i = 0; i < PF; ++i) bufB[i] = pio[(size_t)(PF + i) * H_DIM];
    __builtin_amdgcn_sched_barrier(0);

    for (int s = 0; s < S_LEN; s += 2 * PF) {
#pragma unroll
        for (int u = 0; u < PF; ++u) STEP(bufA[u], s + u);

        if (s + 2 * PF < S_LEN) {
#pragma unroll
            for (int i = 0; i < PF; ++i) bufA[i] = pio[(size_t)(s + 2 * PF + i) * H_DIM];
        }
        __builtin_amdgcn_sched_barrier(0);

#pragma unroll
        for (int u = 0; u < PF; ++u) STEP(bufB[u], s + PF + u);

        if (s + 3 * PF < S_LEN) {
#pragma unroll
            for (int i = 0; i < PF; ++i) bufB[i] = pio[(size_t)(s + 3 * PF + i) * H_DIM];
        }
        __builtin_amdgcn_sched_barrier(0);
    }

    const int chain_idx = chain;
    vout[chain_idx]  = v;
    thout[chain_idx] = theta;
}

extern "C" void kernel_launch(void* const* d_in, const int* in_sizes, int n_in,
                              void* d_out, int out_size, void* d_ws, size_t ws_size,
                              hipStream_t stream) {
    const float* x    = (const float*)d_in[0];
    const float* W    = (const float*)d_in[1];
    const float* bias = (const float*)d_in[2];

    float* out   = (float*)d_out;
    float* vout  = out + (size_t)B_DIM * S_LEN * H_DIM;
    float* thout = vout + B_DIM * H_DIM;

    // GEMM writes dense currents h into the spikes region of d_out.
    dim3 grid(H_DIM / 128, (B_DIM * S_LEN) / 128);
    gemm_kernel<<<grid, 256, 0, stream>>>(x, W, bias, out);

    // Scan reads h and overwrites with spikes in-place; writes v/theta tails.
    scan_kernel<<<64, 64, 0, stream>>>(out, vout, thout);
}